// Round 4
// baseline (1347.127 us; speedup 1.0000x reference)
//
#include <hip/hip_runtime.h>
#include <hip/hip_bf16.h>

// Problem constants (from reference): B=4, S=64, F=64, V=16384, E=512
#define BB 4
#define SS 64
#define FF 64
#define VV 16384
#define EE 512
#define ROWS (BB * SS * FF)   // 16384

// ---------------------------------------------------------------------------
// Kernel 1: transpose W [E,V] -> Wt [V,E] via LDS tile (coalesced both sides)
// ---------------------------------------------------------------------------
#define TILE 32
__global__ __launch_bounds__(256) void transpose_w(const float* __restrict__ W,
                                                   float* __restrict__ Wt) {
    __shared__ float tile[TILE][TILE + 1];
    const int v0 = blockIdx.x * TILE;
    const int e0 = blockIdx.y * TILE;
    const int tx = threadIdx.x;   // 0..31
    const int ty = threadIdx.y;   // 0..7

#pragma unroll
    for (int j = 0; j < TILE; j += 8)
        tile[ty + j][tx] = W[(size_t)(e0 + ty + j) * VV + v0 + tx];
    __syncthreads();
#pragma unroll
    for (int j = 0; j < TILE; j += 8)
        Wt[(size_t)(v0 + ty + j) * EE + e0 + tx] = tile[tx][ty + j];
}

// ---------------------------------------------------------------------------
// Kernel 2: parallel one-hot extract. x is exactly one-hot per row, so
// exactly ONE thread grid-wide finds a nonzero for each row -> plain
// winner-write of ids[row]. No init, no atomics, no races. Pure stream.
// Block = 256 threads covers 4096 consecutive floats (1024 float4);
// each thread: 4 coalesced float4 loads at stride 256.
// Grid = 2^28 floats / 4096 = 65536 blocks.
// ---------------------------------------------------------------------------
__global__ __launch_bounds__(256) void find_ids(const float* __restrict__ x,
                                                int* __restrict__ ids) {
    const float4* x4 = (const float4*)x;
    const size_t base4 = (size_t)blockIdx.x * 1024;   // float4 units
    int found = -1;
#pragma unroll
    for (int j = 0; j < 4; ++j) {
        const size_t off = base4 + (size_t)j * 256 + threadIdx.x;
        float4 v = x4[off];
        int p = -1;
        if (v.x != 0.0f) p = 0;
        if (v.y != 0.0f) p = 1;
        if (v.z != 0.0f) p = 2;
        if (v.w != 0.0f) p = 3;
        if (p >= 0) found = (int)(off << 2) + p;      // global float index
    }
    if (found >= 0) {
        const int row = found >> 14;                  // / VV (=2^14)
        ids[row] = found & (VV - 1);
    }
}

// ---------------------------------------------------------------------------
// Kernel 3: out[row,:] = Wt[ids[row],:] + pos_emb[s,:] + fmap_emb[f,:]
// One wave per row, 2 waves per 128-thread block.
// ---------------------------------------------------------------------------
__global__ __launch_bounds__(128) void embed_rows(
        const int* __restrict__ ids,
        const float* __restrict__ Wt,
        const float* __restrict__ pos_emb,
        const float* __restrict__ fmap_emb,
        float* __restrict__ out) {
    const int lane = threadIdx.x & 63;
    const int wave = threadIdx.x >> 6;
    const int row  = blockIdx.x * 2 + wave;
    const int idx  = ids[row];

    const int f = row & (FF - 1);
    const int s = (row >> 6) & (SS - 1);
    const float4* wrow = (const float4*)(Wt + (size_t)idx * EE);
    const float4* prow = (const float4*)(pos_emb  + (size_t)s * EE);
    const float4* frow = (const float4*)(fmap_emb + (size_t)f * EE);
    float4*       orow = (float4*)(out + (size_t)row * EE);

#pragma unroll
    for (int j = 0; j < 2; ++j) {
        const int e4 = j * 64 + lane;
        float4 w = wrow[e4];
        float4 p = prow[e4];
        float4 fm = frow[e4];
        orow[e4] = make_float4(w.x + p.x + fm.x, w.y + p.y + fm.y,
                               w.z + p.z + fm.z, w.w + p.w + fm.w);
    }
}

// ---------------------------------------------------------------------------
// Fallback (ws too small): one wave per row, early-exit scan + direct
// strided gather from W [E,V].
// ---------------------------------------------------------------------------
__global__ __launch_bounds__(128) void combined_fallback(
        const float* __restrict__ x,
        const float* __restrict__ W,
        const float* __restrict__ pos_emb,
        const float* __restrict__ fmap_emb,
        float* __restrict__ out) {
    const int lane = threadIdx.x & 63;
    const int wave = threadIdx.x >> 6;
    const int row  = blockIdx.x * 2 + wave;

    const float4* xr = (const float4*)(x + (size_t)row * VV);
    int idx = 0;
#pragma unroll 1
    for (int it = 0; it < VV / 256; ++it) {
        float4 v = xr[it * 64 + lane];
        int p = -1;
        if (v.x != 0.0f) p = 0;
        if (v.y != 0.0f) p = 1;
        if (v.z != 0.0f) p = 2;
        if (v.w != 0.0f) p = 3;
        unsigned long long m = __ballot(p >= 0);
        if (m) {
            const int src = (int)__ffsll(m) - 1;
            const int pl  = __shfl(p, src);
            idx = it * 256 + src * 4 + pl;
            break;
        }
    }

    const int f = row & (FF - 1);
    const int s = (row >> 6) & (SS - 1);
    const float4* prow = (const float4*)(pos_emb  + (size_t)s * EE);
    const float4* frow = (const float4*)(fmap_emb + (size_t)f * EE);
    float4*       orow = (float4*)(out + (size_t)row * EE);
#pragma unroll
    for (int j = 0; j < 2; ++j) {
        const int e4 = j * 64 + lane;
        float4 p = prow[e4];
        float4 fm = frow[e4];
        float4 w;
        w.x = W[(size_t)(e4 * 4 + 0) * VV + idx];
        w.y = W[(size_t)(e4 * 4 + 1) * VV + idx];
        w.z = W[(size_t)(e4 * 4 + 2) * VV + idx];
        w.w = W[(size_t)(e4 * 4 + 3) * VV + idx];
        orow[e4] = make_float4(w.x + p.x + fm.x, w.y + p.y + fm.y,
                               w.z + p.z + fm.z, w.w + p.w + fm.w);
    }
}

extern "C" void kernel_launch(void* const* d_in, const int* in_sizes, int n_in,
                              void* d_out, int out_size, void* d_ws, size_t ws_size,
                              hipStream_t stream) {
    const float* x        = (const float*)d_in[0];  // [B,S,F,V]
    const float* W        = (const float*)d_in[1];  // [E,V]
    const float* pos_emb  = (const float*)d_in[2];  // [256,E]
    const float* fmap_emb = (const float*)d_in[3];  // [256,E]
    float* out = (float*)d_out;                     // [B,S,F,E]

    const size_t wt_bytes  = (size_t)VV * EE * sizeof(float);   // 33.55 MB
    const size_t ids_bytes = (size_t)ROWS * sizeof(int);        // 64 KB

    if (ws_size >= wt_bytes + ids_bytes) {
        float* Wt  = (float*)d_ws;
        int*   ids = (int*)((char*)d_ws + wt_bytes);

        dim3 tgrid(VV / TILE, EE / TILE);   // (512, 16)
        dim3 tblock(32, 8);
        transpose_w<<<tgrid, tblock, 0, stream>>>(W, Wt);

        const int nblocks = (BB * SS * FF * VV) / 4096;   // 65536
        find_ids<<<nblocks, 256, 0, stream>>>(x, ids);

        embed_rows<<<ROWS / 2, 128, 0, stream>>>(ids, Wt, pos_emb, fmap_emb, out);
    } else {
        combined_fallback<<<ROWS / 2, 128, 0, stream>>>(x, W, pos_emb, fmap_emb, out);
    }
}

// Round 6
// 1294.633 us; speedup vs baseline: 1.0405x; 1.0405x over previous
//
#include <hip/hip_runtime.h>
#include <hip/hip_bf16.h>

// Problem constants (from reference): B=4, S=64, F=64, V=16384, E=512
#define BB 4
#define SS 64
#define FF 64
#define VV 16384
#define EE 512
#define ROWS (BB * SS * FF)   // 16384

// ---------------------------------------------------------------------------
// Kernel 1: transpose W [E,V] -> Wt [V,E] via LDS tile (coalesced both sides)
// ---------------------------------------------------------------------------
#define TILE 32
__global__ __launch_bounds__(256) void transpose_w(const float* __restrict__ W,
                                                   float* __restrict__ Wt) {
    __shared__ float tile[TILE][TILE + 1];
    const int v0 = blockIdx.x * TILE;
    const int e0 = blockIdx.y * TILE;
    const int tx = threadIdx.x;   // 0..31
    const int ty = threadIdx.y;   // 0..7

#pragma unroll
    for (int j = 0; j < TILE; j += 8)
        tile[ty + j][tx] = W[(size_t)(e0 + ty + j) * VV + v0 + tx];
    __syncthreads();
#pragma unroll
    for (int j = 0; j < TILE; j += 8)
        Wt[(size_t)(v0 + ty + j) * EE + e0 + tx] = tile[tx][ty + j];
}

// ---------------------------------------------------------------------------
// Kernel 2: one wave per (b,s,f) row, 2 waves per 128-thread block.
//   Preload pos/fmap fragments (idx-independent).
//   Phase A: early-exit scan of x row in 4 KB super-chunks, depth-2 prefetch.
//   Phase B: out[row,:] = Wt[idx,:] + pos + fmap (only Wt load waits on idx).
// Expected x read = 50% of row = information-theoretic floor for a uniform
// one-hot index. TLP (64 waves/CU of work) hides the per-wave serial chain
// (verified: 1KB-serial vs 4KB-prefetch scan timed identical in R2/R3).
// ---------------------------------------------------------------------------
__global__ __launch_bounds__(128) void combined_embed(
        const float* __restrict__ x,
        const float* __restrict__ W,      // [E,V] (fallback path)
        const float* __restrict__ Wt,     // [V,E] (fast path)
        const float* __restrict__ pos_emb,
        const float* __restrict__ fmap_emb,
        float* __restrict__ out,
        int use_wt) {
    const int lane = threadIdx.x & 63;
    const int wave = threadIdx.x >> 6;
    const int row  = blockIdx.x * 2 + wave;   // 0 .. ROWS-1

    // ---- Preload idx-independent embed fragments (8 floats/lane each) ----
    const int f = row & (FF - 1);
    const int s = (row >> 6) & (SS - 1);
    const float4* prow = (const float4*)(pos_emb  + (size_t)s * EE);
    const float4* frow = (const float4*)(fmap_emb + (size_t)f * EE);
    float4 p0 = prow[lane],       p1 = prow[64 + lane];
    float4 f0 = frow[lane],       f1 = frow[64 + lane];

    // ---- Phase A: find one-hot index in x[row, :] ----
    const float4* xr = (const float4*)(x + (size_t)row * VV);
    const int NIT = VV / 1024;                // 16 iterations of 1024 floats
    float4 c0 = xr[lane];
    float4 c1 = xr[64 + lane];
    float4 c2 = xr[128 + lane];
    float4 c3 = xr[192 + lane];

    int idx = 0;
#pragma unroll 1
    for (int it = 0; it < NIT; ++it) {
        float4 n0, n1, n2, n3;                // prefetch next 4 KB chunk
        if (it + 1 < NIT) {
            const float4* nx = xr + (it + 1) * 256;
            n0 = nx[lane];
            n1 = nx[64 + lane];
            n2 = nx[128 + lane];
            n3 = nx[192 + lane];
        }
        int p = -1;
        if (c0.x != 0.0f) p = 0;
        if (c0.y != 0.0f) p = 1;
        if (c0.z != 0.0f) p = 2;
        if (c0.w != 0.0f) p = 3;
        if (c1.x != 0.0f) p = 4;
        if (c1.y != 0.0f) p = 5;
        if (c1.z != 0.0f) p = 6;
        if (c1.w != 0.0f) p = 7;
        if (c2.x != 0.0f) p = 8;
        if (c2.y != 0.0f) p = 9;
        if (c2.z != 0.0f) p = 10;
        if (c2.w != 0.0f) p = 11;
        if (c3.x != 0.0f) p = 12;
        if (c3.y != 0.0f) p = 13;
        if (c3.z != 0.0f) p = 14;
        if (c3.w != 0.0f) p = 15;

        unsigned long long m = __ballot(p >= 0);
        if (m) {
            const int src = (int)__ffsll(m) - 1;       // lane holding the hot elt
            const int pl  = __shfl(p, src);            // its slot 0..15
            idx = it * 1024 + ((pl >> 2) << 8) + (src << 2) + (pl & 3);
            break;
        }
        c0 = n0; c1 = n1; c2 = n2; c3 = n3;
    }

    // ---- Phase B: gather + add + store (512 floats, 8 per lane) ----
    float4* orow = (float4*)(out + (size_t)row * EE);

    if (use_wt) {
        const float4* wrow = (const float4*)(Wt + (size_t)idx * EE);
        float4 w0 = wrow[lane];
        float4 w1 = wrow[64 + lane];
        orow[lane]      = make_float4(w0.x + p0.x + f0.x, w0.y + p0.y + f0.y,
                                      w0.z + p0.z + f0.z, w0.w + p0.w + f0.w);
        orow[64 + lane] = make_float4(w1.x + p1.x + f1.x, w1.y + p1.y + f1.y,
                                      w1.z + p1.z + f1.z, w1.w + p1.w + f1.w);
    } else {
        // Fallback: strided column gather from W [E,V]
#pragma unroll
        for (int j = 0; j < 2; ++j) {
            const int e4 = j * 64 + lane;
            float4 pp = (j == 0) ? p0 : p1;
            float4 ff = (j == 0) ? f0 : f1;
            float4 w;
            w.x = W[(size_t)(e4 * 4 + 0) * VV + idx];
            w.y = W[(size_t)(e4 * 4 + 1) * VV + idx];
            w.z = W[(size_t)(e4 * 4 + 2) * VV + idx];
            w.w = W[(size_t)(e4 * 4 + 3) * VV + idx];
            orow[e4] = make_float4(w.x + pp.x + ff.x, w.y + pp.y + ff.y,
                                   w.z + pp.z + ff.z, w.w + pp.w + ff.w);
        }
    }
}

extern "C" void kernel_launch(void* const* d_in, const int* in_sizes, int n_in,
                              void* d_out, int out_size, void* d_ws, size_t ws_size,
                              hipStream_t stream) {
    const float* x        = (const float*)d_in[0];  // [B,S,F,V]
    const float* W        = (const float*)d_in[1];  // [E,V]
    const float* pos_emb  = (const float*)d_in[2];  // [256,E]
    const float* fmap_emb = (const float*)d_in[3];  // [256,E]
    float* out = (float*)d_out;                     // [B,S,F,E]

    const size_t wt_bytes = (size_t)VV * EE * sizeof(float);  // 33.55 MB
    const int use_wt = (ws_size >= wt_bytes) ? 1 : 0;
    float* Wt = (float*)d_ws;

    if (use_wt) {
        dim3 tgrid(VV / TILE, EE / TILE);   // (512, 16)
        dim3 tblock(32, 8);
        transpose_w<<<tgrid, tblock, 0, stream>>>(W, Wt);
    }

    combined_embed<<<ROWS / 2, 128, 0, stream>>>(x, W, Wt, pos_emb, fmap_emb,
                                                 out, use_wt);
}